// Round 6
// baseline (331.724 us; speedup 1.0000x reference)
//
#include <hip/hip_runtime.h>

#define N_NODES 50000
#define N_EDGES 1600000
#define IN_DIM 256
#define OUT_DIM 128
#define NEG_SLOPE 0.01f

#define RB    32                         // rows per bucket
#define NBUCK ((N_NODES + RB - 1) / RB)  // 1563 buckets
#define EPB   (N_EDGES / 256)            // 6250 edges per scatter block
#define CAP   1536                       // max records/bucket (mean 1024, sd 32)

// ---------------------------------------------------------------------------
// Kernel 1: h = x @ W   (fp32, LDS-tiled; no fp32 MFMA on CDNA4)
// ---------------------------------------------------------------------------
#define TM 64
#define TK 32

__global__ __launch_bounds__(256) void gemm_xw(const float* __restrict__ x,
                                               const float* __restrict__ w,
                                               float* __restrict__ h) {
    __shared__ float xs[TK][TM + 1];
    __shared__ float ws[TK][OUT_DIM + 4];

    const int tid  = threadIdx.x;
    const int row0 = blockIdx.x * TM;
    const int tx = tid & 15;
    const int ty = tid >> 4;

    float acc[4][8];
#pragma unroll
    for (int i = 0; i < 4; ++i)
#pragma unroll
        for (int j = 0; j < 8; ++j) acc[i][j] = 0.0f;

    const int loadRow = tid >> 2;
    const int loadK   = (tid & 3) * 8;
    const int wkr  = tid >> 5;
    const int wcol = (tid & 31) * 4;

    for (int kc = 0; kc < IN_DIM; kc += TK) {
        float4 xv0, xv1;
        const int gr = row0 + loadRow;
        if (gr < N_NODES) {
            const float4* xp = (const float4*)(x + (size_t)gr * IN_DIM + kc + loadK);
            xv0 = xp[0];
            xv1 = xp[1];
        } else {
            xv0 = make_float4(0.f, 0.f, 0.f, 0.f);
            xv1 = xv0;
        }
        xs[loadK + 0][loadRow] = xv0.x;
        xs[loadK + 1][loadRow] = xv0.y;
        xs[loadK + 2][loadRow] = xv0.z;
        xs[loadK + 3][loadRow] = xv0.w;
        xs[loadK + 4][loadRow] = xv1.x;
        xs[loadK + 5][loadRow] = xv1.y;
        xs[loadK + 6][loadRow] = xv1.z;
        xs[loadK + 7][loadRow] = xv1.w;

#pragma unroll
        for (int r = 0; r < 4; ++r) {
            const float4* wp = (const float4*)(w + (size_t)(kc + wkr + r * 8) * OUT_DIM + wcol);
            *(float4*)&ws[wkr + r * 8][wcol] = *wp;
        }
        __syncthreads();

#pragma unroll
        for (int k = 0; k < TK; ++k) {
            float xr[4];
            float wr[8];
#pragma unroll
            for (int i = 0; i < 4; ++i) xr[i] = xs[k][ty * 4 + i];
#pragma unroll
            for (int j = 0; j < 8; ++j) wr[j] = ws[k][tx * 8 + j];
#pragma unroll
            for (int i = 0; i < 4; ++i)
#pragma unroll
                for (int j = 0; j < 8; ++j) acc[i][j] += xr[i] * wr[j];
        }
        __syncthreads();
    }

#pragma unroll
    for (int i = 0; i < 4; ++i) {
        const int gr = row0 + ty * 4 + i;
        if (gr < N_NODES) {
            float* hp = h + (size_t)gr * OUT_DIM + tx * 8;
            ((float4*)hp)[0] = make_float4(acc[i][0], acc[i][1], acc[i][2], acc[i][3]);
            ((float4*)hp)[1] = make_float4(acc[i][4], acc[i][5], acc[i][6], acc[i][7]);
        }
    }
}

// ---------------------------------------------------------------------------
// Kernel 2: per-bucket histogram (LDS-staged int atomics, one global atomic
// per block-bucket).
// ---------------------------------------------------------------------------
__global__ __launch_bounds__(256) void bucket_hist(const int* __restrict__ rows,
                                                   int* __restrict__ counts) {
    __shared__ int lhist[NBUCK];
    const int t = threadIdx.x;
    const int ebase = blockIdx.x * EPB;

    for (int b = t; b < NBUCK; b += 256) lhist[b] = 0;
    __syncthreads();

    for (int k = 0; k < EPB; k += 256) {
        if (k + t < EPB) atomicAdd(&lhist[rows[ebase + k + t] / RB], 1);
    }
    __syncthreads();

    for (int b = t; b < NBUCK; b += 256) {
        const int c = lhist[b];
        if (c > 0) atomicAdd(&counts[b], c);
    }
}

// ---------------------------------------------------------------------------
// Kernel 3: exclusive scan of 1563 bucket counts -> offsets[1564] + cursor.
// 1024 threads x 2 buckets each.
// ---------------------------------------------------------------------------
__global__ __launch_bounds__(1024) void scan_buckets(const int* __restrict__ counts,
                                                     int* __restrict__ offsets,
                                                     int* __restrict__ cursor) {
    __shared__ int s[1024];
    const int t = threadIdx.x;
    const int i0 = 2 * t, i1 = 2 * t + 1;
    const int v0 = (i0 < NBUCK) ? counts[i0] : 0;
    const int v1 = (i1 < NBUCK) ? counts[i1] : 0;
    s[t] = v0 + v1;
    __syncthreads();
    for (int off = 1; off < 1024; off <<= 1) {
        int u = (t >= off) ? s[t - off] : 0;
        __syncthreads();
        s[t] += u;
        __syncthreads();
    }
    const int excl = s[t] - (v0 + v1);
    if (i0 < NBUCK) { offsets[i0] = excl;      cursor[i0] = excl; }
    if (i1 < NBUCK) { offsets[i1] = excl + v0; cursor[i1] = excl + v0; }
    if (t == 1023) offsets[NBUCK] = s[t];
}

// ---------------------------------------------------------------------------
// Kernel 4: bucket scatter. Per block: LDS hist of its 6250 edges -> reserve
// contiguous per-bucket ranges -> write packed 8B records
// { col | (row%RB)<<16 , val } grouped by bucket.
// ---------------------------------------------------------------------------
__global__ __launch_bounds__(256) void bucket_scatter(const int* __restrict__ rows,
                                                      const int* __restrict__ cols,
                                                      const float* __restrict__ vals,
                                                      int* __restrict__ cursor,
                                                      int2* __restrict__ ebuf) {
    __shared__ int lcur[NBUCK];
    const int t = threadIdx.x;
    const int ebase = blockIdx.x * EPB;

    for (int b = t; b < NBUCK; b += 256) lcur[b] = 0;
    __syncthreads();

    for (int k = 0; k < EPB; k += 256) {
        if (k + t < EPB) atomicAdd(&lcur[rows[ebase + k + t] / RB], 1);
    }
    __syncthreads();

    for (int b = t; b < NBUCK; b += 256) {
        const int c = lcur[b];
        lcur[b] = (c > 0) ? atomicAdd(&cursor[b], c) : 0;
    }
    __syncthreads();

    for (int k = 0; k < EPB; k += 256) {
        if (k + t < EPB) {
            const int e = ebase + k + t;
            const int r = rows[e];
            const int b = r / RB;
            const int pos = atomicAdd(&lcur[b], 1);
            ebuf[pos] = make_int2(cols[e] | ((r & (RB - 1)) << 16), __float_as_int(vals[e]));
        }
    }
}

// ---------------------------------------------------------------------------
// Kernel 5: bucket gather v4 — 32-row buckets (grid 1563, fully co-resident;
// round-5 was grid-limited at 782 blocks = 3/CU). Counting sort straight
// from global ebuf into ~12.3 KB LDS, then pure register accumulation (no fp
// atomics). Wave owns 8 rows; lane owns dims (2*lane, 2*lane+1). Fused
// leaky-ReLU, out written exactly once.
// ---------------------------------------------------------------------------
__global__ __launch_bounds__(256) void bucket_gather(const float* __restrict__ h,
                                                     const int* __restrict__ offsets,
                                                     const int2* __restrict__ ebuf,
                                                     float* __restrict__ out) {
    __shared__ int2 srec[CAP];      // 12.3 KB sorted-by-row records
    __shared__ int  hist[RB];       // per-row count -> cursor
    __shared__ int  rowoff[RB + 1];

    const int t    = threadIdx.x;
    const int bkt  = blockIdx.x;
    const int wave = t >> 6;
    const int lane = t & 63;

    const int base = offsets[bkt];
    const int cnt  = offsets[bkt + 1] - base;

    if (t < RB) hist[t] = 0;
    __syncthreads();

    if (cnt <= CAP) {
        // ---- pass 1: per-row histogram straight from global ----
        for (int i = t; i < cnt; i += 256) {
            atomicAdd(&hist[(ebuf[base + i].x >> 16) & (RB - 1)], 1);
        }
        __syncthreads();

        // ---- exclusive scan over RB rows (lanes 0..RB-1 of wave 0) ----
        if (t < RB) {
            const int v = hist[t];
            int s = v;
#pragma unroll
            for (int off = 1; off < RB; off <<= 1) {
                const int u = __shfl_up(s, off);
                if (t >= off) s += u;
            }
            rowoff[t + 1] = s;
            hist[t] = s - v;            // exclusive prefix -> cursor
            if (t == 0) rowoff[0] = 0;
        }
        __syncthreads();

        // ---- pass 2: counting sort global -> LDS ----
        for (int i = t; i < cnt; i += 256) {
            const int2 rec = ebuf[base + i];
            const int pos = atomicAdd(&hist[(rec.x >> 16) & (RB - 1)], 1);
            srec[pos] = rec;
        }
        __syncthreads();

        // ---- per-row register accumulation (8 rows per wave) ----
        for (int rr = 0; rr < RB / 4; ++rr) {
            const int row = wave * (RB / 4) + rr;
            const int beg = rowoff[row];
            const int end = rowoff[row + 1];
            float2 acc0 = make_float2(0.f, 0.f);
            float2 acc1 = make_float2(0.f, 0.f);

            int e = beg;
            for (; e + 4 <= end; e += 4) {
                const int2 r0 = srec[e + 0];
                const int2 r1 = srec[e + 1];
                const int2 r2 = srec[e + 2];
                const int2 r3 = srec[e + 3];
                const float2 m0 = ((const float2*)(h + (size_t)(r0.x & 0xFFFF) * OUT_DIM))[lane];
                const float2 m1 = ((const float2*)(h + (size_t)(r1.x & 0xFFFF) * OUT_DIM))[lane];
                const float2 m2 = ((const float2*)(h + (size_t)(r2.x & 0xFFFF) * OUT_DIM))[lane];
                const float2 m3 = ((const float2*)(h + (size_t)(r3.x & 0xFFFF) * OUT_DIM))[lane];
                const float v0 = __int_as_float(r0.y);
                const float v1 = __int_as_float(r1.y);
                const float v2 = __int_as_float(r2.y);
                const float v3 = __int_as_float(r3.y);
                acc0.x += v0 * m0.x; acc0.y += v0 * m0.y;
                acc1.x += v1 * m1.x; acc1.y += v1 * m1.y;
                acc0.x += v2 * m2.x; acc0.y += v2 * m2.y;
                acc1.x += v3 * m3.x; acc1.y += v3 * m3.y;
            }
            for (; e < end; ++e) {
                const int2 r0 = srec[e];
                const float2 m0 = ((const float2*)(h + (size_t)(r0.x & 0xFFFF) * OUT_DIM))[lane];
                const float v0 = __int_as_float(r0.y);
                acc0.x += v0 * m0.x; acc0.y += v0 * m0.y;
            }

            float2 acc = make_float2(acc0.x + acc1.x, acc0.y + acc1.y);
            const int grow = bkt * RB + row;
            if (grow < N_NODES) {
                acc.x = acc.x >= 0.f ? acc.x : NEG_SLOPE * acc.x;
                acc.y = acc.y >= 0.f ? acc.y : NEG_SLOPE * acc.y;
                ((float2*)(out + (size_t)grow * OUT_DIM))[lane] = acc;
            }
        }
    } else {
        // ---- overflow fallback (statistically unreachable; correctness net) ----
        for (int rr = 0; rr < RB / 4; ++rr) {
            const int row = wave * (RB / 4) + rr;
            float2 acc = make_float2(0.f, 0.f);
            for (int e = 0; e < cnt; ++e) {
                const int2 rec = ebuf[base + e];
                if (((rec.x >> 16) & (RB - 1)) == row) {
                    const float2 m = ((const float2*)(h + (size_t)(rec.x & 0xFFFF) * OUT_DIM))[lane];
                    const float v = __int_as_float(rec.y);
                    acc.x += v * m.x; acc.y += v * m.y;
                }
            }
            const int grow = bkt * RB + row;
            if (grow < N_NODES) {
                acc.x = acc.x >= 0.f ? acc.x : NEG_SLOPE * acc.x;
                acc.y = acc.y >= 0.f ? acc.y : NEG_SLOPE * acc.y;
                ((float2*)(out + (size_t)grow * OUT_DIM))[lane] = acc;
            }
        }
    }
}

// ---------------------------------------------------------------------------
// Launch
// ---------------------------------------------------------------------------
extern "C" void kernel_launch(void* const* d_in, const int* in_sizes, int n_in,
                              void* d_out, int out_size, void* d_ws, size_t ws_size,
                              hipStream_t stream) {
    const float* x    = (const float*)d_in[0];
    const float* w    = (const float*)d_in[1];
    const float* vals = (const float*)d_in[2];
    const int*   rows = (const int*)d_in[3];
    const int*   cols = (const int*)d_in[4];
    float* out = (float*)d_out;

    char* ws = (char*)d_ws;
    size_t off = 0;
    auto alloc = [&](size_t bytes) {
        void* p = ws + off;
        off = (off + bytes + 255) & ~(size_t)255;
        return p;
    };
    float* h       = (float*)alloc((size_t)N_NODES * OUT_DIM * sizeof(float)); // 25.6 MB
    int2*  ebuf    = (int2*) alloc((size_t)N_EDGES * sizeof(int2));            // 12.8 MB
    int*   counts  = (int*)  alloc((size_t)NBUCK * sizeof(int));
    int*   offsets = (int*)  alloc((size_t)(NBUCK + 1) * sizeof(int));
    int*   cursor  = (int*)  alloc((size_t)NBUCK * sizeof(int));

    hipMemsetAsync(counts, 0, (size_t)NBUCK * sizeof(int), stream);

    const int gemm_blocks = (N_NODES + TM - 1) / TM;
    gemm_xw<<<gemm_blocks, 256, 0, stream>>>(x, w, h);

    bucket_hist<<<256, 256, 0, stream>>>(rows, counts);
    scan_buckets<<<1, 1024, 0, stream>>>(counts, offsets, cursor);
    bucket_scatter<<<256, 256, 0, stream>>>(rows, cols, vals, cursor, ebuf);
    bucket_gather<<<NBUCK, 256, 0, stream>>>(h, offsets, ebuf, out);
}

// Round 7
// 325.041 us; speedup vs baseline: 1.0206x; 1.0206x over previous
//
#include <hip/hip_runtime.h>
#include <hip/hip_fp16.h>

#define N_NODES 50000
#define N_EDGES 1600000
#define IN_DIM 256
#define OUT_DIM 128
#define NEG_SLOPE 0.01f

#define RB    32                         // rows per bucket
#define NBUCK ((N_NODES + RB - 1) / RB)  // 1563 buckets
#define EPB   (N_EDGES / 256)            // 6250 edges per scatter block
#define CAP   1536                       // max records/bucket (mean 1024, sd 32)

// ---------------------------------------------------------------------------
// Kernel 1: h = x @ W  (fp32 accumulate, fp16 store — halves gather traffic;
// |h| <~ 7 so fp16 range/precision is ample vs 0.435 absmax threshold)
// ---------------------------------------------------------------------------
#define TM 64
#define TK 32

__global__ __launch_bounds__(256) void gemm_xw(const float* __restrict__ x,
                                               const float* __restrict__ w,
                                               __half* __restrict__ h) {
    __shared__ float xs[TK][TM + 1];
    __shared__ float ws[TK][OUT_DIM + 4];

    const int tid  = threadIdx.x;
    const int row0 = blockIdx.x * TM;
    const int tx = tid & 15;
    const int ty = tid >> 4;

    float acc[4][8];
#pragma unroll
    for (int i = 0; i < 4; ++i)
#pragma unroll
        for (int j = 0; j < 8; ++j) acc[i][j] = 0.0f;

    const int loadRow = tid >> 2;
    const int loadK   = (tid & 3) * 8;
    const int wkr  = tid >> 5;
    const int wcol = (tid & 31) * 4;

    for (int kc = 0; kc < IN_DIM; kc += TK) {
        float4 xv0, xv1;
        const int gr = row0 + loadRow;
        if (gr < N_NODES) {
            const float4* xp = (const float4*)(x + (size_t)gr * IN_DIM + kc + loadK);
            xv0 = xp[0];
            xv1 = xp[1];
        } else {
            xv0 = make_float4(0.f, 0.f, 0.f, 0.f);
            xv1 = xv0;
        }
        xs[loadK + 0][loadRow] = xv0.x;
        xs[loadK + 1][loadRow] = xv0.y;
        xs[loadK + 2][loadRow] = xv0.z;
        xs[loadK + 3][loadRow] = xv0.w;
        xs[loadK + 4][loadRow] = xv1.x;
        xs[loadK + 5][loadRow] = xv1.y;
        xs[loadK + 6][loadRow] = xv1.z;
        xs[loadK + 7][loadRow] = xv1.w;

#pragma unroll
        for (int r = 0; r < 4; ++r) {
            const float4* wp = (const float4*)(w + (size_t)(kc + wkr + r * 8) * OUT_DIM + wcol);
            *(float4*)&ws[wkr + r * 8][wcol] = *wp;
        }
        __syncthreads();

#pragma unroll
        for (int k = 0; k < TK; ++k) {
            float xr[4];
            float wr[8];
#pragma unroll
            for (int i = 0; i < 4; ++i) xr[i] = xs[k][ty * 4 + i];
#pragma unroll
            for (int j = 0; j < 8; ++j) wr[j] = ws[k][tx * 8 + j];
#pragma unroll
            for (int i = 0; i < 4; ++i)
#pragma unroll
                for (int j = 0; j < 8; ++j) acc[i][j] += xr[i] * wr[j];
        }
        __syncthreads();
    }

#pragma unroll
    for (int i = 0; i < 4; ++i) {
        const int gr = row0 + ty * 4 + i;
        if (gr < N_NODES) {
            __half2 o[4];
            o[0] = __float22half2_rn(make_float2(acc[i][0], acc[i][1]));
            o[1] = __float22half2_rn(make_float2(acc[i][2], acc[i][3]));
            o[2] = __float22half2_rn(make_float2(acc[i][4], acc[i][5]));
            o[3] = __float22half2_rn(make_float2(acc[i][6], acc[i][7]));
            *(int4*)(h + (size_t)gr * OUT_DIM + tx * 8) = *(const int4*)o;
        }
    }
}

// ---------------------------------------------------------------------------
// Kernel 2: per-bucket histogram (LDS-staged) + global per-row counts
// (rowcnt is L2-hot, 50k addresses -> low contention int atomics).
// ---------------------------------------------------------------------------
__global__ __launch_bounds__(256) void bucket_hist(const int* __restrict__ rows,
                                                   int* __restrict__ counts,
                                                   int* __restrict__ rowcnt) {
    __shared__ int lhist[NBUCK];
    const int t = threadIdx.x;
    const int ebase = blockIdx.x * EPB;

    for (int b = t; b < NBUCK; b += 256) lhist[b] = 0;
    __syncthreads();

    for (int k = 0; k < EPB; k += 256) {
        if (k + t < EPB) {
            const int r = rows[ebase + k + t];
            atomicAdd(&lhist[r / RB], 1);
            atomicAdd(&rowcnt[r], 1);
        }
    }
    __syncthreads();

    for (int b = t; b < NBUCK; b += 256) {
        const int c = lhist[b];
        if (c > 0) atomicAdd(&counts[b], c);
    }
}

// ---------------------------------------------------------------------------
// Kernel 3: exclusive scan of 1563 bucket counts -> offsets[1564] + cursor.
// ---------------------------------------------------------------------------
__global__ __launch_bounds__(1024) void scan_buckets(const int* __restrict__ counts,
                                                     int* __restrict__ offsets,
                                                     int* __restrict__ cursor) {
    __shared__ int s[1024];
    const int t = threadIdx.x;
    const int i0 = 2 * t, i1 = 2 * t + 1;
    const int v0 = (i0 < NBUCK) ? counts[i0] : 0;
    const int v1 = (i1 < NBUCK) ? counts[i1] : 0;
    s[t] = v0 + v1;
    __syncthreads();
    for (int off = 1; off < 1024; off <<= 1) {
        int u = (t >= off) ? s[t - off] : 0;
        __syncthreads();
        s[t] += u;
        __syncthreads();
    }
    const int excl = s[t] - (v0 + v1);
    if (i0 < NBUCK) { offsets[i0] = excl;      cursor[i0] = excl; }
    if (i1 < NBUCK) { offsets[i1] = excl + v0; cursor[i1] = excl + v0; }
    if (t == 1023) offsets[NBUCK] = s[t];
}

// ---------------------------------------------------------------------------
// Kernel 4: bucket scatter. Per block: LDS hist of its 6250 edges -> reserve
// contiguous per-bucket ranges -> write packed 8B records
// { col | (row%RB)<<16 , val } grouped by bucket.
// ---------------------------------------------------------------------------
__global__ __launch_bounds__(256) void bucket_scatter(const int* __restrict__ rows,
                                                      const int* __restrict__ cols,
                                                      const float* __restrict__ vals,
                                                      int* __restrict__ cursor,
                                                      int2* __restrict__ ebuf) {
    __shared__ int lcur[NBUCK];
    const int t = threadIdx.x;
    const int ebase = blockIdx.x * EPB;

    for (int b = t; b < NBUCK; b += 256) lcur[b] = 0;
    __syncthreads();

    for (int k = 0; k < EPB; k += 256) {
        if (k + t < EPB) atomicAdd(&lcur[rows[ebase + k + t] / RB], 1);
    }
    __syncthreads();

    for (int b = t; b < NBUCK; b += 256) {
        const int c = lcur[b];
        lcur[b] = (c > 0) ? atomicAdd(&cursor[b], c) : 0;
    }
    __syncthreads();

    for (int k = 0; k < EPB; k += 256) {
        if (k + t < EPB) {
            const int e = ebase + k + t;
            const int r = rows[e];
            const int b = r / RB;
            const int pos = atomicAdd(&lcur[b], 1);
            ebuf[pos] = make_int2(cols[e] | ((r & (RB - 1)) << 16), __float_as_int(vals[e]));
        }
    }
}

// ---------------------------------------------------------------------------
// Kernel 5: bucket gather v5 — fp16 h (halves the saturated ~3.4 TB/s fetch
// stream), single ebuf pass (row offsets come from precomputed rowcnt).
// Counting sort into ~12.3 KB LDS, pure register accumulation, fused
// leaky-ReLU, out written exactly once. No fp atomics anywhere.
// ---------------------------------------------------------------------------
__global__ __launch_bounds__(256) void bucket_gather(const __half* __restrict__ h,
                                                     const int* __restrict__ offsets,
                                                     const int* __restrict__ rowcnt,
                                                     const int2* __restrict__ ebuf,
                                                     float* __restrict__ out) {
    __shared__ int2 srec[CAP];      // 12.3 KB sorted-by-row records
    __shared__ int  hist[RB];       // sort cursors
    __shared__ int  rowoff[RB + 1];

    const int t    = threadIdx.x;
    const int bkt  = blockIdx.x;
    const int wave = t >> 6;
    const int lane = t & 63;

    const int base = offsets[bkt];
    const int cnt  = offsets[bkt + 1] - base;

    // ---- row offsets from rowcnt (no ebuf pre-pass) ----
    if (t < RB) {
        const int gr = bkt * RB + t;
        const int v = (gr < N_NODES) ? rowcnt[gr] : 0;
        int s = v;
#pragma unroll
        for (int off = 1; off < RB; off <<= 1) {
            const int u = __shfl_up(s, off);
            if (t >= off) s += u;
        }
        rowoff[t + 1] = s;
        hist[t] = s - v;            // exclusive prefix -> sort cursor
        if (t == 0) rowoff[0] = 0;
    }
    __syncthreads();

    if (cnt <= CAP) {
        // ---- counting sort: global ebuf -> LDS srec (single pass) ----
        for (int i = t; i < cnt; i += 256) {
            const int2 rec = ebuf[base + i];
            const int pos = atomicAdd(&hist[(rec.x >> 16) & (RB - 1)], 1);
            srec[pos] = rec;
        }
        __syncthreads();

        // ---- per-row register accumulation (8 rows per wave) ----
        for (int rr = 0; rr < RB / 4; ++rr) {
            const int row = wave * (RB / 4) + rr;
            const int beg = rowoff[row];
            const int end = rowoff[row + 1];
            float2 acc0 = make_float2(0.f, 0.f);
            float2 acc1 = make_float2(0.f, 0.f);

            int e = beg;
            for (; e + 4 <= end; e += 4) {
                const int2 r0 = srec[e + 0];
                const int2 r1 = srec[e + 1];
                const int2 r2 = srec[e + 2];
                const int2 r3 = srec[e + 3];
                const float2 m0 = __half22float2(((const __half2*)(h + (size_t)(r0.x & 0xFFFF) * OUT_DIM))[lane]);
                const float2 m1 = __half22float2(((const __half2*)(h + (size_t)(r1.x & 0xFFFF) * OUT_DIM))[lane]);
                const float2 m2 = __half22float2(((const __half2*)(h + (size_t)(r2.x & 0xFFFF) * OUT_DIM))[lane]);
                const float2 m3 = __half22float2(((const __half2*)(h + (size_t)(r3.x & 0xFFFF) * OUT_DIM))[lane]);
                const float v0 = __int_as_float(r0.y);
                const float v1 = __int_as_float(r1.y);
                const float v2 = __int_as_float(r2.y);
                const float v3 = __int_as_float(r3.y);
                acc0.x += v0 * m0.x; acc0.y += v0 * m0.y;
                acc1.x += v1 * m1.x; acc1.y += v1 * m1.y;
                acc0.x += v2 * m2.x; acc0.y += v2 * m2.y;
                acc1.x += v3 * m3.x; acc1.y += v3 * m3.y;
            }
            for (; e < end; ++e) {
                const int2 r0 = srec[e];
                const float2 m0 = __half22float2(((const __half2*)(h + (size_t)(r0.x & 0xFFFF) * OUT_DIM))[lane]);
                const float v0 = __int_as_float(r0.y);
                acc0.x += v0 * m0.x; acc0.y += v0 * m0.y;
            }

            float2 acc = make_float2(acc0.x + acc1.x, acc0.y + acc1.y);
            const int grow = bkt * RB + row;
            if (grow < N_NODES) {
                acc.x = acc.x >= 0.f ? acc.x : NEG_SLOPE * acc.x;
                acc.y = acc.y >= 0.f ? acc.y : NEG_SLOPE * acc.y;
                ((float2*)(out + (size_t)grow * OUT_DIM))[lane] = acc;
            }
        }
    } else {
        // ---- overflow fallback (statistically unreachable; correctness net) ----
        for (int rr = 0; rr < RB / 4; ++rr) {
            const int row = wave * (RB / 4) + rr;
            float2 acc = make_float2(0.f, 0.f);
            for (int e = 0; e < cnt; ++e) {
                const int2 rec = ebuf[base + e];
                if (((rec.x >> 16) & (RB - 1)) == row) {
                    const float2 m = __half22float2(((const __half2*)(h + (size_t)(rec.x & 0xFFFF) * OUT_DIM))[lane]);
                    const float v = __int_as_float(rec.y);
                    acc.x += v * m.x; acc.y += v * m.y;
                }
            }
            const int grow = bkt * RB + row;
            if (grow < N_NODES) {
                acc.x = acc.x >= 0.f ? acc.x : NEG_SLOPE * acc.x;
                acc.y = acc.y >= 0.f ? acc.y : NEG_SLOPE * acc.y;
                ((float2*)(out + (size_t)grow * OUT_DIM))[lane] = acc;
            }
        }
    }
}

// ---------------------------------------------------------------------------
// Launch
// ---------------------------------------------------------------------------
extern "C" void kernel_launch(void* const* d_in, const int* in_sizes, int n_in,
                              void* d_out, int out_size, void* d_ws, size_t ws_size,
                              hipStream_t stream) {
    const float* x    = (const float*)d_in[0];
    const float* w    = (const float*)d_in[1];
    const float* vals = (const float*)d_in[2];
    const int*   rows = (const int*)d_in[3];
    const int*   cols = (const int*)d_in[4];
    float* out = (float*)d_out;

    char* ws = (char*)d_ws;
    size_t off = 0;
    auto alloc = [&](size_t bytes) {
        void* p = ws + off;
        off = (off + bytes + 255) & ~(size_t)255;
        return p;
    };
    __half* h      = (__half*)alloc((size_t)N_NODES * OUT_DIM * sizeof(__half)); // 12.8 MB
    int2*  ebuf    = (int2*) alloc((size_t)N_EDGES * sizeof(int2));              // 12.8 MB
    int*   counts  = (int*)  alloc((size_t)NBUCK * sizeof(int));
    int*   offsets = (int*)  alloc((size_t)(NBUCK + 1) * sizeof(int));
    int*   cursor  = (int*)  alloc((size_t)NBUCK * sizeof(int));
    int*   rowcnt  = (int*)  alloc((size_t)N_NODES * sizeof(int));               // 200 KB

    hipMemsetAsync(counts, 0, (size_t)NBUCK * sizeof(int), stream);
    hipMemsetAsync(rowcnt, 0, (size_t)N_NODES * sizeof(int), stream);

    const int gemm_blocks = (N_NODES + TM - 1) / TM;
    gemm_xw<<<gemm_blocks, 256, 0, stream>>>(x, w, h);

    bucket_hist<<<256, 256, 0, stream>>>(rows, counts, rowcnt);
    scan_buckets<<<1, 1024, 0, stream>>>(counts, offsets, cursor);
    bucket_scatter<<<256, 256, 0, stream>>>(rows, cols, vals, cursor, ebuf);
    bucket_gather<<<NBUCK, 256, 0, stream>>>(h, offsets, rowcnt, ebuf, out);
}

// Round 8
// 273.533 us; speedup vs baseline: 1.2127x; 1.1883x over previous
//
#include <hip/hip_runtime.h>
#include <hip/hip_fp16.h>

#define N_NODES 50000
#define N_EDGES 1600000
#define IN_DIM 256
#define OUT_DIM 128
#define NEG_SLOPE 0.01f

#define RB    32                         // rows per bucket
#define NBUCK ((N_NODES + RB - 1) / RB)  // 1563 buckets
#define CAP   1536                       // max records/bucket (mean 1024, sd 32)

#define HIST_BLOCKS 256
#define EPB_H (N_EDGES / HIST_BLOCKS)    // 6250
#define SCAT_BLOCKS 512
#define EPB_S (N_EDGES / SCAT_BLOCKS)    // 3125
#define SCAT_ITERS ((EPB_S + 255) / 256) // 13

// ---------------------------------------------------------------------------
// Kernel 1: h = x @ W  (fp32 accumulate, fp16 store — halves gather traffic;
// |h| <~ 7 so fp16 range/precision is ample vs 0.435 absmax threshold)
// ---------------------------------------------------------------------------
#define TM 64
#define TK 32

__global__ __launch_bounds__(256) void gemm_xw(const float* __restrict__ x,
                                               const float* __restrict__ w,
                                               __half* __restrict__ h) {
    __shared__ float xs[TK][TM + 1];
    __shared__ float ws[TK][OUT_DIM + 4];

    const int tid  = threadIdx.x;
    const int row0 = blockIdx.x * TM;
    const int tx = tid & 15;
    const int ty = tid >> 4;

    float acc[4][8];
#pragma unroll
    for (int i = 0; i < 4; ++i)
#pragma unroll
        for (int j = 0; j < 8; ++j) acc[i][j] = 0.0f;

    const int loadRow = tid >> 2;
    const int loadK   = (tid & 3) * 8;
    const int wkr  = tid >> 5;
    const int wcol = (tid & 31) * 4;

    for (int kc = 0; kc < IN_DIM; kc += TK) {
        float4 xv0, xv1;
        const int gr = row0 + loadRow;
        if (gr < N_NODES) {
            const float4* xp = (const float4*)(x + (size_t)gr * IN_DIM + kc + loadK);
            xv0 = xp[0];
            xv1 = xp[1];
        } else {
            xv0 = make_float4(0.f, 0.f, 0.f, 0.f);
            xv1 = xv0;
        }
        xs[loadK + 0][loadRow] = xv0.x;
        xs[loadK + 1][loadRow] = xv0.y;
        xs[loadK + 2][loadRow] = xv0.z;
        xs[loadK + 3][loadRow] = xv0.w;
        xs[loadK + 4][loadRow] = xv1.x;
        xs[loadK + 5][loadRow] = xv1.y;
        xs[loadK + 6][loadRow] = xv1.z;
        xs[loadK + 7][loadRow] = xv1.w;

#pragma unroll
        for (int r = 0; r < 4; ++r) {
            const float4* wp = (const float4*)(w + (size_t)(kc + wkr + r * 8) * OUT_DIM + wcol);
            *(float4*)&ws[wkr + r * 8][wcol] = *wp;
        }
        __syncthreads();

#pragma unroll
        for (int k = 0; k < TK; ++k) {
            float xr[4];
            float wr[8];
#pragma unroll
            for (int i = 0; i < 4; ++i) xr[i] = xs[k][ty * 4 + i];
#pragma unroll
            for (int j = 0; j < 8; ++j) wr[j] = ws[k][tx * 8 + j];
#pragma unroll
            for (int i = 0; i < 4; ++i)
#pragma unroll
                for (int j = 0; j < 8; ++j) acc[i][j] += xr[i] * wr[j];
        }
        __syncthreads();
    }

#pragma unroll
    for (int i = 0; i < 4; ++i) {
        const int gr = row0 + ty * 4 + i;
        if (gr < N_NODES) {
            __half2 o[4];
            o[0] = __float22half2_rn(make_float2(acc[i][0], acc[i][1]));
            o[1] = __float22half2_rn(make_float2(acc[i][2], acc[i][3]));
            o[2] = __float22half2_rn(make_float2(acc[i][4], acc[i][5]));
            o[3] = __float22half2_rn(make_float2(acc[i][6], acc[i][7]));
            *(int4*)(h + (size_t)gr * OUT_DIM + tx * 8) = *(const int4*)o;
        }
    }
}

// ---------------------------------------------------------------------------
// Kernel 2: per-bucket histogram (LDS-staged int atomics, one global atomic
// per nonzero block-bucket). No per-row global atomics (round-7 rowcnt RMWs
// cost 51 MB of HBM writeback -> 73 us).
// ---------------------------------------------------------------------------
__global__ __launch_bounds__(256) void bucket_hist(const int* __restrict__ rows,
                                                   int* __restrict__ counts) {
    __shared__ int lhist[NBUCK];
    const int t = threadIdx.x;
    const int ebase = blockIdx.x * EPB_H;

    for (int b = t; b < NBUCK; b += 256) lhist[b] = 0;
    __syncthreads();

    for (int k = 0; k < EPB_H; k += 256) {
        if (k + t < EPB_H) atomicAdd(&lhist[rows[ebase + k + t] / RB], 1);
    }
    __syncthreads();

    for (int b = t; b < NBUCK; b += 256) {
        const int c = lhist[b];
        if (c > 0) atomicAdd(&counts[b], c);
    }
}

// ---------------------------------------------------------------------------
// Kernel 3: exclusive scan of 1563 bucket counts -> offsets[1564] + cursor.
// ---------------------------------------------------------------------------
__global__ __launch_bounds__(1024) void scan_buckets(const int* __restrict__ counts,
                                                     int* __restrict__ offsets,
                                                     int* __restrict__ cursor) {
    __shared__ int s[1024];
    const int t = threadIdx.x;
    const int i0 = 2 * t, i1 = 2 * t + 1;
    const int v0 = (i0 < NBUCK) ? counts[i0] : 0;
    const int v1 = (i1 < NBUCK) ? counts[i1] : 0;
    s[t] = v0 + v1;
    __syncthreads();
    for (int off = 1; off < 1024; off <<= 1) {
        int u = (t >= off) ? s[t - off] : 0;
        __syncthreads();
        s[t] += u;
        __syncthreads();
    }
    const int excl = s[t] - (v0 + v1);
    if (i0 < NBUCK) { offsets[i0] = excl;      cursor[i0] = excl; }
    if (i1 < NBUCK) { offsets[i1] = excl + v0; cursor[i1] = excl + v0; }
    if (t == 1023) offsets[NBUCK] = s[t];
}

// ---------------------------------------------------------------------------
// Kernel 4: bucket scatter. 512 blocks (2/CU) for latency hiding; row
// indices register-cached between passes (single rows[] read). Per block:
// LDS hist -> reserve contiguous per-bucket ranges -> write packed 8B
// records { col | (row%RB)<<16 , val } grouped by bucket.
// ---------------------------------------------------------------------------
__global__ __launch_bounds__(256) void bucket_scatter(const int* __restrict__ rows,
                                                      const int* __restrict__ cols,
                                                      const float* __restrict__ vals,
                                                      int* __restrict__ cursor,
                                                      int2* __restrict__ ebuf) {
    __shared__ int lcur[NBUCK];
    const int t = threadIdx.x;
    const int ebase = blockIdx.x * EPB_S;

    for (int b = t; b < NBUCK; b += 256) lcur[b] = 0;
    __syncthreads();

    int myr[SCAT_ITERS];
#pragma unroll
    for (int k = 0; k < SCAT_ITERS; ++k) {
        const int i = k * 256 + t;
        myr[k] = -1;
        if (i < EPB_S) {
            const int r = rows[ebase + i];
            myr[k] = r;
            atomicAdd(&lcur[r / RB], 1);
        }
    }
    __syncthreads();

    for (int b = t; b < NBUCK; b += 256) {
        const int c = lcur[b];
        lcur[b] = (c > 0) ? atomicAdd(&cursor[b], c) : 0;
    }
    __syncthreads();

#pragma unroll
    for (int k = 0; k < SCAT_ITERS; ++k) {
        const int i = k * 256 + t;
        if (i < EPB_S) {
            const int e = ebase + i;
            const int r = myr[k];
            const int pos = atomicAdd(&lcur[r / RB], 1);
            ebuf[pos] = make_int2(cols[e] | ((r & (RB - 1)) << 16), __float_as_int(vals[e]));
        }
    }
}

// ---------------------------------------------------------------------------
// Kernel 5: bucket gather — two-pass counting sort from L2-hot ebuf (pass 1:
// per-row LDS histogram; pass 2: sort into ~12.3 KB LDS), then pure register
// accumulation over fp16 h. Fused leaky-ReLU, out written exactly once.
// No fp atomics, no per-row global atomics.
// ---------------------------------------------------------------------------
__global__ __launch_bounds__(256) void bucket_gather(const __half* __restrict__ h,
                                                     const int* __restrict__ offsets,
                                                     const int2* __restrict__ ebuf,
                                                     float* __restrict__ out) {
    __shared__ int2 srec[CAP];      // 12.3 KB sorted-by-row records
    __shared__ int  hist[RB];       // per-row count -> sort cursor
    __shared__ int  rowoff[RB + 1];

    const int t    = threadIdx.x;
    const int bkt  = blockIdx.x;
    const int wave = t >> 6;
    const int lane = t & 63;

    const int base = offsets[bkt];
    const int cnt  = offsets[bkt + 1] - base;

    if (t < RB) hist[t] = 0;
    __syncthreads();

    if (cnt <= CAP) {
        // ---- pass 1: per-row histogram from ebuf (keys only) ----
        const int* ekey = (const int*)ebuf;
        for (int i = t; i < cnt; i += 256) {
            atomicAdd(&hist[(ekey[2 * (base + i)] >> 16) & (RB - 1)], 1);
        }
        __syncthreads();

        // ---- exclusive scan over RB rows (lanes 0..RB-1 of wave 0) ----
        if (t < RB) {
            const int v = hist[t];
            int s = v;
#pragma unroll
            for (int off = 1; off < RB; off <<= 1) {
                const int u = __shfl_up(s, off);
                if (t >= off) s += u;
            }
            rowoff[t + 1] = s;
            hist[t] = s - v;            // exclusive prefix -> sort cursor
            if (t == 0) rowoff[0] = 0;
        }
        __syncthreads();

        // ---- pass 2: counting sort global -> LDS ----
        for (int i = t; i < cnt; i += 256) {
            const int2 rec = ebuf[base + i];
            const int pos = atomicAdd(&hist[(rec.x >> 16) & (RB - 1)], 1);
            srec[pos] = rec;
        }
        __syncthreads();

        // ---- per-row register accumulation (8 rows per wave) ----
        for (int rr = 0; rr < RB / 4; ++rr) {
            const int row = wave * (RB / 4) + rr;
            const int beg = rowoff[row];
            const int end = rowoff[row + 1];
            float2 acc0 = make_float2(0.f, 0.f);
            float2 acc1 = make_float2(0.f, 0.f);

            int e = beg;
            for (; e + 4 <= end; e += 4) {
                const int2 r0 = srec[e + 0];
                const int2 r1 = srec[e + 1];
                const int2 r2 = srec[e + 2];
                const int2 r3 = srec[e + 3];
                const float2 m0 = __half22float2(((const __half2*)(h + (size_t)(r0.x & 0xFFFF) * OUT_DIM))[lane]);
                const float2 m1 = __half22float2(((const __half2*)(h + (size_t)(r1.x & 0xFFFF) * OUT_DIM))[lane]);
                const float2 m2 = __half22float2(((const __half2*)(h + (size_t)(r2.x & 0xFFFF) * OUT_DIM))[lane]);
                const float2 m3 = __half22float2(((const __half2*)(h + (size_t)(r3.x & 0xFFFF) * OUT_DIM))[lane]);
                const float v0 = __int_as_float(r0.y);
                const float v1 = __int_as_float(r1.y);
                const float v2 = __int_as_float(r2.y);
                const float v3 = __int_as_float(r3.y);
                acc0.x += v0 * m0.x; acc0.y += v0 * m0.y;
                acc1.x += v1 * m1.x; acc1.y += v1 * m1.y;
                acc0.x += v2 * m2.x; acc0.y += v2 * m2.y;
                acc1.x += v3 * m3.x; acc1.y += v3 * m3.y;
            }
            for (; e < end; ++e) {
                const int2 r0 = srec[e];
                const float2 m0 = __half22float2(((const __half2*)(h + (size_t)(r0.x & 0xFFFF) * OUT_DIM))[lane]);
                const float v0 = __int_as_float(r0.y);
                acc0.x += v0 * m0.x; acc0.y += v0 * m0.y;
            }

            float2 acc = make_float2(acc0.x + acc1.x, acc0.y + acc1.y);
            const int grow = bkt * RB + row;
            if (grow < N_NODES) {
                acc.x = acc.x >= 0.f ? acc.x : NEG_SLOPE * acc.x;
                acc.y = acc.y >= 0.f ? acc.y : NEG_SLOPE * acc.y;
                ((float2*)(out + (size_t)grow * OUT_DIM))[lane] = acc;
            }
        }
    } else {
        // ---- overflow fallback (statistically unreachable; correctness net) ----
        for (int rr = 0; rr < RB / 4; ++rr) {
            const int row = wave * (RB / 4) + rr;
            float2 acc = make_float2(0.f, 0.f);
            for (int e = 0; e < cnt; ++e) {
                const int2 rec = ebuf[base + e];
                if (((rec.x >> 16) & (RB - 1)) == row) {
                    const float2 m = __half22float2(((const __half2*)(h + (size_t)(rec.x & 0xFFFF) * OUT_DIM))[lane]);
                    const float v = __int_as_float(rec.y);
                    acc.x += v * m.x; acc.y += v * m.y;
                }
            }
            const int grow = bkt * RB + row;
            if (grow < N_NODES) {
                acc.x = acc.x >= 0.f ? acc.x : NEG_SLOPE * acc.x;
                acc.y = acc.y >= 0.f ? acc.y : NEG_SLOPE * acc.y;
                ((float2*)(out + (size_t)grow * OUT_DIM))[lane] = acc;
            }
        }
    }
}

// ---------------------------------------------------------------------------
// Launch
// ---------------------------------------------------------------------------
extern "C" void kernel_launch(void* const* d_in, const int* in_sizes, int n_in,
                              void* d_out, int out_size, void* d_ws, size_t ws_size,
                              hipStream_t stream) {
    const float* x    = (const float*)d_in[0];
    const float* w    = (const float*)d_in[1];
    const float* vals = (const float*)d_in[2];
    const int*   rows = (const int*)d_in[3];
    const int*   cols = (const int*)d_in[4];
    float* out = (float*)d_out;

    char* ws = (char*)d_ws;
    size_t off = 0;
    auto alloc = [&](size_t bytes) {
        void* p = ws + off;
        off = (off + bytes + 255) & ~(size_t)255;
        return p;
    };
    __half* h      = (__half*)alloc((size_t)N_NODES * OUT_DIM * sizeof(__half)); // 12.8 MB
    int2*  ebuf    = (int2*) alloc((size_t)N_EDGES * sizeof(int2));              // 12.8 MB
    int*   counts  = (int*)  alloc((size_t)NBUCK * sizeof(int));
    int*   offsets = (int*)  alloc((size_t)(NBUCK + 1) * sizeof(int));
    int*   cursor  = (int*)  alloc((size_t)NBUCK * sizeof(int));

    hipMemsetAsync(counts, 0, (size_t)NBUCK * sizeof(int), stream);

    const int gemm_blocks = (N_NODES + TM - 1) / TM;
    gemm_xw<<<gemm_blocks, 256, 0, stream>>>(x, w, h);

    bucket_hist<<<HIST_BLOCKS, 256, 0, stream>>>(rows, counts);
    scan_buckets<<<1, 1024, 0, stream>>>(counts, offsets, cursor);
    bucket_scatter<<<SCAT_BLOCKS, 256, 0, stream>>>(rows, cols, vals, cursor, ebuf);
    bucket_gather<<<NBUCK, 256, 0, stream>>>(h, offsets, ebuf, out);
}